// Round 7
// baseline (284.317 us; speedup 1.0000x reference)
//
#include <hip/hip_runtime.h>
#include <hip/hip_bf16.h>
#include <stdint.h>

#define S_LEN  1500
#define S_PAD  1536
#define BATCH  4
#define NSTATE 1024
#define NHEAD  16
#define HDIM   64
#define MROWS  6000   // BATCH * S_LEN
#define C1     0.180336879f   // 0.125 * log2(e), folded into q at projection

typedef __attribute__((ext_vector_type(8)))  short short8;    // 8 bf16 = 4 VGPRs
typedef __attribute__((ext_vector_type(4)))  float floatx4;
typedef __attribute__((ext_vector_type(16))) float floatx16;

__device__ __forceinline__ unsigned short f2bf(float f) {
  union { float f; unsigned int u; } v; v.f = f;
  unsigned int r = v.u + 0x7fffu + ((v.u >> 16) & 1u);
  return (unsigned short)(r >> 16);
}

// async global->LDS, 16B per lane: lane i reads its own global addr, writes
// wave-uniform LDS base + i*16.
__device__ __forceinline__ void gld_lds16(const void* g, void* l) {
  __builtin_amdgcn_global_load_lds(
      (const __attribute__((address_space(1))) void*)g,
      (__attribute__((address_space(3))) void*)l, 16, 0, 0);
}

// ---------------------------------------------------------------------------
// fp32 -> bf16 for x + 4 weight matrices, one launch.
// ---------------------------------------------------------------------------
__global__ __launch_bounds__(256) void cvt_all(
    const float* __restrict__ x,  const float* __restrict__ Wq,
    const float* __restrict__ Wk, const float* __restrict__ Wv,
    const float* __restrict__ Wo, unsigned short* __restrict__ dst)
{
  const size_t NX = (size_t)MROWS * NSTATE;
  size_t e = ((size_t)blockIdx.x * 256 + threadIdx.x) * 4;
  const float* src; size_t off;
  if (e < NX) { src = x; off = e; }
  else {
    size_t t = e - NX;
    int wsel = (int)(t >> 20);           // NW = 2^20
    off = t & ((1u << 20) - 1);
    src = (wsel == 0) ? Wq : (wsel == 1) ? Wk : (wsel == 2) ? Wv : Wo;
  }
  float4 v = *(const float4*)(src + off);
  uint2 o;
  o.x = (unsigned int)f2bf(v.x) | ((unsigned int)f2bf(v.y) << 16);
  o.y = (unsigned int)f2bf(v.z) | ((unsigned int)f2bf(v.w) << 16);
  *(uint2*)(dst + e) = o;
}

// ---------------------------------------------------------------------------
// GEMM: Y[m,n] = (sum_k X[m,k]*W[n,k] + bias[n]) * scale; bf16 in, fp32 accum.
// 128x128 tile, 4 waves, BK=64 as two m97-layout BK=32 half-buffers.
// ---------------------------------------------------------------------------
template <bool F32OUT>
__device__ __forceinline__ void gemm128_bt(
    const unsigned short* __restrict__ X,
    const unsigned short* __restrict__ W,
    const float* __restrict__ bias,
    void* __restrict__ Yv,
    int m0, int n0, float scale)
{
  __shared__ unsigned short As[2][128 * 32];   // 8 KB each
  __shared__ unsigned short Bs[2][128 * 32];

  const int tid  = threadIdx.x;
  const int lane = tid & 63;
  const int wid  = tid >> 6;
  const int wm   = (wid & 1) * 64;
  const int wn   = (wid >> 1) * 64;
  const int l15  = lane & 15;
  const int l4   = lane >> 4;

  floatx4 acc[4][4];
#pragma unroll
  for (int i = 0; i < 4; ++i)
#pragma unroll
    for (int j = 0; j < 4; ++j)
      acc[i][j] = (floatx4){0.f, 0.f, 0.f, 0.f};

  const int srow  = tid >> 2;        // 0..63
  const int scolb = (tid & 3) * 16;  // byte offset within 64B K-row

  const char* xrp[2];
  const char* wrp[2];
#pragma unroll
  for (int r = 0; r < 2; ++r) {
    int arow = m0 + r * 64 + srow;
    if (arow > MROWS - 1) arow = MROWS - 1;
    xrp[r] = (const char*)X + (size_t)arow * NSTATE * 2 + scolb;
    int brow = n0 + r * 64 + srow;   // N always full
    wrp[r] = (const char*)W + (size_t)brow * NSTATE * 2 + scolb;
  }

  for (int k0 = 0; k0 < NSTATE; k0 += 64) {
    __syncthreads();
#pragma unroll
    for (int h = 0; h < 2; ++h) {
      int kb = (k0 + h * 32) * 2;
#pragma unroll
      for (int r = 0; r < 2; ++r) {
        gld_lds16(xrp[r] + kb, (char*)As[h] + r * 4096 + wid * 1024);
        gld_lds16(wrp[r] + kb, (char*)Bs[h] + r * 4096 + wid * 1024);
      }
    }
    __syncthreads();

#pragma unroll
    for (int h = 0; h < 2; ++h) {
      short8 a[4], b[4];
#pragma unroll
      for (int i = 0; i < 4; ++i)
        a[i] = *(const short8*)(As[h] + (wm + i * 16 + l15) * 32 + l4 * 8);
#pragma unroll
      for (int j = 0; j < 4; ++j)
        b[j] = *(const short8*)(Bs[h] + (wn + j * 16 + l15) * 32 + l4 * 8);
#pragma unroll
      for (int i = 0; i < 4; ++i)
#pragma unroll
        for (int j = 0; j < 4; ++j)
          acc[i][j] = __builtin_amdgcn_mfma_f32_16x16x32_bf16(a[i], b[j], acc[i][j], 0, 0, 0);
    }
  }

  // epilogue: C/D layout row=(lane>>4)*4+r, col=lane&15
#pragma unroll
  for (int j = 0; j < 4; ++j) {
    int ng = n0 + wn + j * 16 + l15;
    float bias_v = bias ? bias[ng] : 0.f;
#pragma unroll
    for (int i = 0; i < 4; ++i) {
      int mgb = m0 + wm + i * 16 + l4 * 4;
#pragma unroll
      for (int r = 0; r < 4; ++r) {
        int mg = mgb + r;
        if (mg < MROWS) {
          float val = (acc[i][j][r] + bias_v) * scale;
          if (F32OUT) ((float*)Yv)[(size_t)mg * NSTATE + ng] = val;
          else        ((unsigned short*)Yv)[(size_t)mg * NSTATE + ng] = f2bf(val);
        }
      }
    }
  }
}

// grid: (n-tiles, m-tiles, z) -- consecutive blocks share the X slab (L2 reuse)
__global__ __launch_bounds__(256) void proj_qkv(
    const unsigned short* __restrict__ X,
    const unsigned short* __restrict__ Wq, const unsigned short* __restrict__ Wk,
    const unsigned short* __restrict__ Wv,
    const float* __restrict__ bq, const float* __restrict__ bv,
    unsigned short* __restrict__ q, unsigned short* __restrict__ k,
    unsigned short* __restrict__ v)
{
  const int z = blockIdx.z;
  const unsigned short* W = (z == 0) ? Wq : (z == 1) ? Wk : Wv;
  const float* bias       = (z == 0) ? bq : (z == 1) ? (const float*)nullptr : bv;
  unsigned short* Y       = (z == 0) ? q  : (z == 1) ? k  : v;
  float scale             = (z == 0) ? C1 : 1.0f;   // fold 0.125*log2(e) into q
  gemm128_bt<false>(X, W, bias, Y, blockIdx.y * 128, blockIdx.x * 128, scale);
}

__global__ __launch_bounds__(256) void proj_o(
    const unsigned short* __restrict__ X, const unsigned short* __restrict__ W,
    const float* __restrict__ bias, float* __restrict__ Y)
{
  gemm128_bt<true>(X, W, bias, Y, blockIdx.y * 128, blockIdx.x * 128, 1.0f);
}

// ---------------------------------------------------------------------------
// V transpose: [B,S,H*D] -> Vt[B,H,D,S_PAD], zero-padded past S_LEN.
// ---------------------------------------------------------------------------
__global__ __launch_bounds__(256) void vtrans(
    const unsigned short* __restrict__ v, unsigned short* __restrict__ vt)
{
  __shared__ unsigned short T[64][72];
  const int tid = threadIdx.x;
  const int st = blockIdx.x * 64, h = blockIdx.y, b = blockIdx.z;
#pragma unroll
  for (int rr = 0; rr < 2; ++rr) {
    int sl = rr * 32 + (tid >> 3);
    int dl = (tid & 7) * 8;
    int s  = st + sl;
    uint4 val = make_uint4(0u, 0u, 0u, 0u);
    if (s < S_LEN)
      val = *(const uint4*)&v[((size_t)b * S_LEN + s) * NSTATE + h * HDIM + dl];
    *(uint4*)&T[sl][dl] = val;
  }
  __syncthreads();
#pragma unroll
  for (int rr = 0; rr < 2; ++rr) {
    int dl = rr * 32 + (tid >> 3);
    int s0 = (tid & 7) * 8;
    unsigned short tmp[8];
#pragma unroll
    for (int j2 = 0; j2 < 8; ++j2) tmp[j2] = T[s0 + j2][dl];
    *(uint4*)&vt[(((size_t)b * NHEAD + h) * HDIM + dl) * S_PAD + st + s0] =
        *(const uint4*)tmp;
  }
}

// ---------------------------------------------------------------------------
// Flash attention, transposed-score form (32x32x16 MFMA).
//   S^T = K . Q^T  (q pre-scaled by C1: p = exp2(s) directly)
//   O^T = V^T . P^T; l via ones-row MFMA (exact compensation of RNE-rounded P)
// ---------------------------------------------------------------------------
__global__ __launch_bounds__(256, 4) void attn32t(
    const unsigned short* __restrict__ Q, const unsigned short* __restrict__ K,
    const unsigned short* __restrict__ VT, unsigned short* __restrict__ O)
{
  __shared__ unsigned short SMEM[16384];      // 32 KB
  unsigned short* Ks  = SMEM;                 // [128 kv][64 d], 16B-chunk xor-swizzled
  unsigned short* Vts = SMEM + 8192;          // [64 d][128 kv], 16B-chunk xor-swizzled
  unsigned short* Os  = SMEM;                 // epilogue overlay [128 q][72]

  const int tid  = threadIdx.x;
  const int lane = tid & 63;
  const int w    = tid >> 6;
  const int l31  = lane & 31;
  const int lhi  = lane >> 5;
  const int qt = blockIdx.x, h = blockIdx.y, b = blockIdx.z;
  const size_t base  = ((size_t)b * S_LEN) * NSTATE + h * HDIM;
  const size_t vbase = (((size_t)b * NHEAD + h) * HDIM) * S_PAD;

  // Q fragments (B-operand): lane holds Q[q=l31][d = c*16 + lhi*8 + j]
  short8 qf[4];
  {
    int qrow = qt * 128 + w * 32 + l31;
    if (qrow > S_LEN - 1) qrow = S_LEN - 1;
    const unsigned short* qp = Q + base + (size_t)qrow * NSTATE;
#pragma unroll
    for (int c = 0; c < 4; ++c)
      qf[c] = *(const short8*)(qp + c * 16 + lhi * 8);
  }

  // all-ones A fragment (bf16 1.0) for the l-accumulating MFMA
  short8 ones;
#pragma unroll
  for (int i = 0; i < 8; ++i) ones[i] = (short)0x3F80;

  floatx16 oacc[2], oacc_l;
  oacc[0] = (floatx16)(0.f);
  oacc[1] = (floatx16)(0.f);
  oacc_l  = (floatx16)(0.f);

  for (int t = 0; t < 12; ++t) {
    __syncthreads();   // previous tile fully consumed
    // stage K tile 128x64: call = 8 rows x 8 chunks, phys chunk = logical^(row&7)
#pragma unroll
    for (int qq = 0; qq < 4; ++qq) {
      int row  = (w * 4 + qq) * 8 + (lane >> 3);
      int logc = (lane & 7) ^ (row & 7);
      int s = t * 128 + row; if (s > S_LEN - 1) s = S_LEN - 1;
      gld_lds16(&K[base + (size_t)s * NSTATE + logc * 8],
                (char*)Ks + (w * 4 + qq) * 1024);
    }
    // stage Vt tile 64x128: call = 4 rows x 16 chunks, phys = logical^(d&7)
#pragma unroll
    for (int qq = 0; qq < 4; ++qq) {
      int d    = (w * 4 + qq) * 4 + (lane >> 4);
      int logc = (lane & 15) ^ (d & 7);
      gld_lds16(&VT[vbase + (size_t)d * S_PAD + t * 128 + logc * 8],
                (char*)Vts + (w * 4 + qq) * 1024);
    }
    __syncthreads();

#pragma unroll
    for (int kvt = 0; kvt < 4; ++kvt) {
      // --- S^T tile: 32 kv x 32 q ---
      floatx16 sacc = (floatx16)(0.f);
#pragma unroll
      for (int c = 0; c < 4; ++c) {
        int row  = kvt * 32 + l31;
        int phys = (c * 2 + lhi) ^ (row & 7);
        short8 ak = *(const short8*)(Ks + row * 64 + phys * 8);
        sacc = __builtin_amdgcn_mfma_f32_32x32x16_bf16(ak, qf[c], sacc, 0, 0, 0);
      }

      // kv masking (only the last iteration's tail)
      if (t == 11 && kvt >= 2) {
        if (kvt == 3) {
#pragma unroll
          for (int r = 0; r < 16; ++r) sacc[r] = -3.0e38f;
        } else {
#pragma unroll
          for (int r = 12; r < 16; ++r) sacc[r] = lhi ? -3.0e38f : sacc[r];
        }
      }

      // p = exp2(s) (q pre-scaled); pack pairs via v_cvt_pk_bf16_f32
      unsigned int pk[8], ex[8];
#pragma unroll
      for (int i = 0; i < 8; ++i) {
        float p0 = exp2f(sacc[2 * i]);
        float p1 = exp2f(sacc[2 * i + 1]);
        __hip_bfloat162 h2 = __float22bfloat162_rn(float2{p0, p1});
        unsigned int u;
        __builtin_memcpy(&u, &h2, 4);
        pk[i] = u;
      }
#pragma unroll
      for (int i = 0; i < 8; ++i)
        ex[i] = __shfl_xor((unsigned int)pk[i], 32, 64);

      // P^T B-fragments
      int4 f0i, f1i;
      f0i.x = lhi ? ex[2] : pk[0];
      f0i.y = lhi ? ex[3] : pk[1];
      f0i.z = lhi ? pk[2] : ex[0];
      f0i.w = lhi ? pk[3] : ex[1];
      f1i.x = lhi ? ex[6] : pk[4];
      f1i.y = lhi ? ex[7] : pk[5];
      f1i.z = lhi ? pk[6] : ex[4];
      f1i.w = lhi ? pk[7] : ex[5];
      short8 f0 = *(short8*)&f0i;
      short8 f1 = *(short8*)&f1i;

      // l accumulation on the MFMA pipe: every D-row of ones.P^T = kv-sum
      oacc_l = __builtin_amdgcn_mfma_f32_32x32x16_bf16(ones, f0, oacc_l, 0, 0, 0);
      oacc_l = __builtin_amdgcn_mfma_f32_32x32x16_bf16(ones, f1, oacc_l, 0, 0, 0);

      // --- O^T += V^T P^T ---
#pragma unroll
      for (int dt = 0; dt < 2; ++dt) {
        int d = dt * 32 + l31;
        int p0 = ((kvt * 4 + 0) + lhi) ^ (d & 7);
        int p1 = ((kvt * 4 + 2) + lhi) ^ (d & 7);
        short8 av0 = *(const short8*)(Vts + d * 128 + p0 * 8);
        short8 av1 = *(const short8*)(Vts + d * 128 + p1 * 8);
        oacc[dt] = __builtin_amdgcn_mfma_f32_32x32x16_bf16(av0, f0, oacc[dt], 0, 0, 0);
        oacc[dt] = __builtin_amdgcn_mfma_f32_32x32x16_bf16(av1, f1, oacc[dt], 0, 0, 0);
      }
    }
  }

  float inv = 1.f / oacc_l[0];   // full kv-sum for this lane's q column

  // epilogue: O^T regs -> LDS transpose -> coalesced global store
  __syncthreads();   // everyone done with Ks/Vts
#pragma unroll
  for (int dt = 0; dt < 2; ++dt)
#pragma unroll
    for (int g = 0; g < 4; ++g) {
      int d0 = dt * 32 + g * 8 + lhi * 4;
      float v0 = oacc[dt][4 * g + 0] * inv;
      float v1 = oacc[dt][4 * g + 1] * inv;
      float v2 = oacc[dt][4 * g + 2] * inv;
      float v3 = oacc[dt][4 * g + 3] * inv;
      uint2 pk2;
      pk2.x = (unsigned int)f2bf(v0) | ((unsigned int)f2bf(v1) << 16);
      pk2.y = (unsigned int)f2bf(v2) | ((unsigned int)f2bf(v3) << 16);
      *(uint2*)&Os[(w * 32 + l31) * 72 + d0] = pk2;
    }
  __syncthreads();
#pragma unroll
  for (int pass = 0; pass < 4; ++pass) {
    int e = pass * 256 + tid;
    int row = e >> 3, ch = e & 7;
    int s = qt * 128 + row;
    if (s < S_LEN)
      *(uint4*)&O[base + (size_t)s * NSTATE + ch * 8] = *(const uint4*)&Os[row * 72 + ch * 8];
  }
}

// ---------------------------------------------------------------------------
extern "C" void kernel_launch(void* const* d_in, const int* in_sizes, int n_in,
                              void* d_out, int out_size, void* d_ws, size_t ws_size,
                              hipStream_t stream) {
  const float* x  = (const float*)d_in[0];
  const float* Wq = (const float*)d_in[1];
  const float* bq = (const float*)d_in[2];
  const float* Wk = (const float*)d_in[3];
  const float* Wv = (const float*)d_in[4];
  const float* bv = (const float*)d_in[5];
  const float* Wo = (const float*)d_in[6];
  const float* bo = (const float*)d_in[7];
  float* out = (float*)d_out;

  const size_t NX = (size_t)MROWS * NSTATE;
  const size_t NW = (size_t)NSTATE * NSTATE;

  unsigned short* xb  = (unsigned short*)d_ws;   // dies after proj_qkv
  unsigned short* Wqb = xb  + NX;
  unsigned short* Wkb = Wqb + NW;
  unsigned short* Wvb = Wkb + NW;
  unsigned short* Wob = Wvb + NW;
  unsigned short* q   = Wob + NW;
  unsigned short* k   = q + NX;
  unsigned short* v   = k + NX;
  unsigned short* vt  = v + NX;
  unsigned short* wv  = xb;                      // alias onto dead xb

  dim3 blk(256);
  const size_t n4_total = (NX + 4 * NW) / 4;
  cvt_all<<<dim3((int)(n4_total / 256)), blk, 0, stream>>>(x, Wq, Wk, Wv, Wo, xb);
  proj_qkv<<<dim3(8, 47, 3), blk, 0, stream>>>(xb, Wqb, Wkb, Wvb, bq, bv, q, k, v);
  vtrans<<<dim3(24, NHEAD, BATCH), blk, 0, stream>>>(v, vt);
  attn32t<<<dim3(12, NHEAD, BATCH), blk, 0, stream>>>(q, k, vt, wv);
  proj_o<<<dim3(8, 47, 1), blk, 0, stream>>>(wv, Wob, bo, out);
}

// Round 8
// 269.611 us; speedup vs baseline: 1.0545x; 1.0545x over previous
//
#include <hip/hip_runtime.h>
#include <hip/hip_bf16.h>
#include <stdint.h>

#define S_LEN  1500
#define S_PAD  1536
#define BATCH  4
#define NSTATE 1024
#define NHEAD  16
#define HDIM   64
#define MROWS  6000   // BATCH * S_LEN
#define C1     0.180336879f   // 0.125 * log2(e), folded into q at projection

typedef __attribute__((ext_vector_type(8)))  short short8;    // 8 bf16 = 4 VGPRs
typedef __attribute__((ext_vector_type(4)))  float floatx4;
typedef __attribute__((ext_vector_type(16))) float floatx16;

__device__ __forceinline__ unsigned short f2bf(float f) {
  union { float f; unsigned int u; } v; v.f = f;
  unsigned int r = v.u + 0x7fffu + ((v.u >> 16) & 1u);
  return (unsigned short)(r >> 16);
}

// async global->LDS, 16B per lane: lane i reads its own global addr, writes
// wave-uniform LDS base + i*16.
__device__ __forceinline__ void gld_lds16(const void* g, void* l) {
  __builtin_amdgcn_global_load_lds(
      (const __attribute__((address_space(1))) void*)g,
      (__attribute__((address_space(3))) void*)l, 16, 0, 0);
}

// ---------------------------------------------------------------------------
// fp32 -> bf16 for x + 4 weight matrices, one launch.
// ---------------------------------------------------------------------------
__global__ __launch_bounds__(256) void cvt_all(
    const float* __restrict__ x,  const float* __restrict__ Wq,
    const float* __restrict__ Wk, const float* __restrict__ Wv,
    const float* __restrict__ Wo, unsigned short* __restrict__ dst)
{
  const size_t NX = (size_t)MROWS * NSTATE;
  size_t e = ((size_t)blockIdx.x * 256 + threadIdx.x) * 4;
  const float* src; size_t off;
  if (e < NX) { src = x; off = e; }
  else {
    size_t t = e - NX;
    int wsel = (int)(t >> 20);           // NW = 2^20
    off = t & ((1u << 20) - 1);
    src = (wsel == 0) ? Wq : (wsel == 1) ? Wk : (wsel == 2) ? Wv : Wo;
  }
  float4 v = *(const float4*)(src + off);
  uint2 o;
  o.x = (unsigned int)f2bf(v.x) | ((unsigned int)f2bf(v.y) << 16);
  o.y = (unsigned int)f2bf(v.z) | ((unsigned int)f2bf(v.w) << 16);
  *(uint2*)(dst + e) = o;
}

// ---------------------------------------------------------------------------
// GEMM: Y[m,n] = (sum_k X[m,k]*W[n,k] + bias[n]) * scale; bf16 in, fp32 accum.
// 128x128 tile, 4 waves, BK=64 as two m97-layout BK=32 half-buffers.
// MODE: 0 = bf16 row-major store, 1 = fp32 row-major store,
//       2 = bf16 store transposed into vt[B,H,D,S_PAD] (V projection).
// ---------------------------------------------------------------------------
template <int MODE>
__device__ __forceinline__ void gemm128_bt(
    const unsigned short* __restrict__ X,
    const unsigned short* __restrict__ W,
    const float* __restrict__ bias,
    void* __restrict__ Yv,
    int m0, int n0, float scale)
{
  // staging uses 16384 shorts (As[2]+Bs[2] of 4096 each);
  // MODE==2 epilogue reuses it as a 128x136 transpose buffer (17408 shorts).
  __shared__ unsigned short SM[17408];
  unsigned short* Asp = SM;            // As[h] = Asp + h*4096
  unsigned short* Bsp = SM + 8192;     // Bs[h] = Bsp + h*4096

  const int tid  = threadIdx.x;
  const int lane = tid & 63;
  const int wid  = tid >> 6;
  const int wm   = (wid & 1) * 64;
  const int wn   = (wid >> 1) * 64;
  const int l15  = lane & 15;
  const int l4   = lane >> 4;

  floatx4 acc[4][4];
#pragma unroll
  for (int i = 0; i < 4; ++i)
#pragma unroll
    for (int j = 0; j < 4; ++j)
      acc[i][j] = (floatx4){0.f, 0.f, 0.f, 0.f};

  const int srow  = tid >> 2;        // 0..63
  const int scolb = (tid & 3) * 16;  // byte offset within 64B K-row

  const char* xrp[2];
  const char* wrp[2];
#pragma unroll
  for (int r = 0; r < 2; ++r) {
    int arow = m0 + r * 64 + srow;
    if (arow > MROWS - 1) arow = MROWS - 1;
    xrp[r] = (const char*)X + (size_t)arow * NSTATE * 2 + scolb;
    int brow = n0 + r * 64 + srow;   // N always full
    wrp[r] = (const char*)W + (size_t)brow * NSTATE * 2 + scolb;
  }

  for (int k0 = 0; k0 < NSTATE; k0 += 64) {
    __syncthreads();
#pragma unroll
    for (int h = 0; h < 2; ++h) {
      int kb = (k0 + h * 32) * 2;
#pragma unroll
      for (int r = 0; r < 2; ++r) {
        gld_lds16(xrp[r] + kb, (char*)SM + h * 8192 + r * 4096 + wid * 1024);
        gld_lds16(wrp[r] + kb, (char*)SM + 16384 + h * 8192 + r * 4096 + wid * 1024);
      }
    }
    __syncthreads();

#pragma unroll
    for (int h = 0; h < 2; ++h) {
      const unsigned short* Ah = Asp + h * 4096;
      const unsigned short* Bh = Bsp + h * 4096;
      short8 a[4], b[4];
#pragma unroll
      for (int i = 0; i < 4; ++i)
        a[i] = *(const short8*)(Ah + (wm + i * 16 + l15) * 32 + l4 * 8);
#pragma unroll
      for (int j = 0; j < 4; ++j)
        b[j] = *(const short8*)(Bh + (wn + j * 16 + l15) * 32 + l4 * 8);
#pragma unroll
      for (int i = 0; i < 4; ++i)
#pragma unroll
        for (int j = 0; j < 4; ++j)
          acc[i][j] = __builtin_amdgcn_mfma_f32_16x16x32_bf16(a[i], b[j], acc[i][j], 0, 0, 0);
    }
  }

  if (MODE != 2) {
    // epilogue: C/D layout row=(lane>>4)*4+r, col=lane&15
#pragma unroll
    for (int j = 0; j < 4; ++j) {
      int ng = n0 + wn + j * 16 + l15;
      float bias_v = bias ? bias[ng] : 0.f;
#pragma unroll
      for (int i = 0; i < 4; ++i) {
        int mgb = m0 + wm + i * 16 + l4 * 4;
#pragma unroll
        for (int r = 0; r < 4; ++r) {
          int mg = mgb + r;
          if (mg < MROWS) {
            float val = (acc[i][j][r] + bias_v) * scale;
            if (MODE == 1) ((float*)Yv)[(size_t)mg * NSTATE + ng] = val;
            else           ((unsigned short*)Yv)[(size_t)mg * NSTATE + ng] = f2bf(val);
          }
        }
      }
    }
  } else {
    // V projection: transpose through LDS, store vt[((b*16+h)*64+d)*S_PAD + s]
    unsigned short* vt = (unsigned short*)Yv;
    __syncthreads();   // staging LDS dead now
#pragma unroll
    for (int j = 0; j < 4; ++j) {
      int nl = wn + j * 16 + l15;
      float bias_v = bias[n0 + nl];
#pragma unroll
      for (int i = 0; i < 4; ++i) {
        int mlb = wm + i * 16 + l4 * 4;
#pragma unroll
        for (int r = 0; r < 4; ++r)
          SM[nl * 136 + mlb + r] = f2bf(acc[i][j][r] + bias_v);
      }
    }
    __syncthreads();
#pragma unroll
    for (int pass = 0; pass < 8; ++pass) {
      int e   = pass * 256 + tid;      // 0..2047
      int nl  = e >> 4;                // 0..127
      int m0l = (e & 15) * 8;          // 0..120
      int ng  = n0 + nl;
      int hh  = ng >> 6, dd = ng & 63;
      int mg  = m0 + m0l;
      int b1  = mg / 1500;
      int s1  = mg - b1 * 1500;
      if (mg + 7 < MROWS && s1 + 7 < S_LEN) {
        *(uint4*)&vt[(((size_t)b1 * NHEAD + hh) * HDIM + dd) * S_PAD + s1] =
            *(const uint4*)&SM[nl * 136 + m0l];
      } else {
#pragma unroll
        for (int jj = 0; jj < 8; ++jj) {
          int m = mg + jj;
          if (m < MROWS) {
            int b2 = m / 1500;
            int s2 = m - b2 * 1500;
            vt[(((size_t)b2 * NHEAD + hh) * HDIM + dd) * S_PAD + s2] =
                SM[nl * 136 + m0l + jj];
          }
        }
      }
    }
  }
}

// grid: (m-tiles=47, n-tiles=8, z=3) -- m-major dispatch (round-5 measured best)
__global__ __launch_bounds__(256) void proj_qkv(
    const unsigned short* __restrict__ X,
    const unsigned short* __restrict__ Wq, const unsigned short* __restrict__ Wk,
    const unsigned short* __restrict__ Wv,
    const float* __restrict__ bq, const float* __restrict__ bv,
    unsigned short* __restrict__ q, unsigned short* __restrict__ k,
    unsigned short* __restrict__ vt)
{
  const int z = blockIdx.z;
  const int m0 = blockIdx.x * 128, n0 = blockIdx.y * 128;
  if (z == 0)      gemm128_bt<0>(X, Wq, bq,      q,  m0, n0, C1);
  else if (z == 1) gemm128_bt<0>(X, Wk, nullptr, k,  m0, n0, 1.0f);
  else             gemm128_bt<2>(X, Wv, bv,      vt, m0, n0, 1.0f);
}

__global__ __launch_bounds__(256) void proj_o(
    const unsigned short* __restrict__ X, const unsigned short* __restrict__ W,
    const float* __restrict__ bias, float* __restrict__ Y)
{
  gemm128_bt<1>(X, W, bias, Y, blockIdx.x * 128, blockIdx.y * 128, 1.0f);
}

// ---------------------------------------------------------------------------
// Flash attention, transposed-score form (32x32x16 MFMA).
//   S^T = K . Q^T  (q pre-scaled by C1: p = exp2(s) directly)
//   O^T = V^T . P^T; l via ones-row MFMA (exact compensation of RNE-rounded P)
// ---------------------------------------------------------------------------
__global__ __launch_bounds__(256, 4) void attn32t(
    const unsigned short* __restrict__ Q, const unsigned short* __restrict__ K,
    const unsigned short* __restrict__ VT, unsigned short* __restrict__ O)
{
  __shared__ unsigned short SMEM[16384];      // 32 KB
  unsigned short* Ks  = SMEM;                 // [128 kv][64 d], 16B-chunk xor-swizzled
  unsigned short* Vts = SMEM + 8192;          // [64 d][128 kv], 16B-chunk xor-swizzled
  unsigned short* Os  = SMEM;                 // epilogue overlay [128 q][72]

  const int tid  = threadIdx.x;
  const int lane = tid & 63;
  const int w    = tid >> 6;
  const int l31  = lane & 31;
  const int lhi  = lane >> 5;
  const int qt = blockIdx.x, h = blockIdx.y, b = blockIdx.z;
  const size_t base  = ((size_t)b * S_LEN) * NSTATE + h * HDIM;
  const size_t vbase = (((size_t)b * NHEAD + h) * HDIM) * S_PAD;

  // Q fragments (B-operand): lane holds Q[q=l31][d = c*16 + lhi*8 + j]
  short8 qf[4];
  {
    int qrow = qt * 128 + w * 32 + l31;
    if (qrow > S_LEN - 1) qrow = S_LEN - 1;
    const unsigned short* qp = Q + base + (size_t)qrow * NSTATE;
#pragma unroll
    for (int c = 0; c < 4; ++c)
      qf[c] = *(const short8*)(qp + c * 16 + lhi * 8);
  }

  // all-ones A fragment (bf16 1.0) for the l-accumulating MFMA
  short8 ones;
#pragma unroll
  for (int i = 0; i < 8; ++i) ones[i] = (short)0x3F80;

  floatx16 oacc[2], oacc_l;
  oacc[0] = (floatx16)(0.f);
  oacc[1] = (floatx16)(0.f);
  oacc_l  = (floatx16)(0.f);

  for (int t = 0; t < 12; ++t) {
    __syncthreads();   // previous tile fully consumed
    // stage K tile 128x64: call = 8 rows x 8 chunks, phys chunk = logical^(row&7)
#pragma unroll
    for (int qq = 0; qq < 4; ++qq) {
      int row  = (w * 4 + qq) * 8 + (lane >> 3);
      int logc = (lane & 7) ^ (row & 7);
      int s = t * 128 + row; if (s > S_LEN - 1) s = S_LEN - 1;
      gld_lds16(&K[base + (size_t)s * NSTATE + logc * 8],
                (char*)Ks + (w * 4 + qq) * 1024);
    }
    // stage Vt tile 64x128: call = 4 rows x 16 chunks, phys = logical^(d&7)
#pragma unroll
    for (int qq = 0; qq < 4; ++qq) {
      int d    = (w * 4 + qq) * 4 + (lane >> 4);
      int logc = (lane & 15) ^ (d & 7);
      gld_lds16(&VT[vbase + (size_t)d * S_PAD + t * 128 + logc * 8],
                (char*)Vts + (w * 4 + qq) * 1024);
    }
    __syncthreads();

#pragma unroll
    for (int kvt = 0; kvt < 4; ++kvt) {
      // --- S^T tile: 32 kv x 32 q ---
      floatx16 sacc = (floatx16)(0.f);
#pragma unroll
      for (int c = 0; c < 4; ++c) {
        int row  = kvt * 32 + l31;
        int phys = (c * 2 + lhi) ^ (row & 7);
        short8 ak = *(const short8*)(Ks + row * 64 + phys * 8);
        sacc = __builtin_amdgcn_mfma_f32_32x32x16_bf16(ak, qf[c], sacc, 0, 0, 0);
      }

      // kv masking (only the last iteration's tail)
      if (t == 11 && kvt >= 2) {
        if (kvt == 3) {
#pragma unroll
          for (int r = 0; r < 16; ++r) sacc[r] = -3.0e38f;
        } else {
#pragma unroll
          for (int r = 12; r < 16; ++r) sacc[r] = lhi ? -3.0e38f : sacc[r];
        }
      }

      // p = exp2(s) (q pre-scaled); pack pairs via v_cvt_pk_bf16_f32
      unsigned int pk[8], ex[8];
#pragma unroll
      for (int i = 0; i < 8; ++i) {
        float p0 = exp2f(sacc[2 * i]);
        float p1 = exp2f(sacc[2 * i + 1]);
        __hip_bfloat162 h2 = __float22bfloat162_rn(float2{p0, p1});
        unsigned int u;
        __builtin_memcpy(&u, &h2, 4);
        pk[i] = u;
      }
#pragma unroll
      for (int i = 0; i < 8; ++i)
        ex[i] = __shfl_xor((unsigned int)pk[i], 32, 64);

      // P^T B-fragments
      int4 f0i, f1i;
      f0i.x = lhi ? ex[2] : pk[0];
      f0i.y = lhi ? ex[3] : pk[1];
      f0i.z = lhi ? pk[2] : ex[0];
      f0i.w = lhi ? pk[3] : ex[1];
      f1i.x = lhi ? ex[6] : pk[4];
      f1i.y = lhi ? ex[7] : pk[5];
      f1i.z = lhi ? pk[6] : ex[4];
      f1i.w = lhi ? pk[7] : ex[5];
      short8 f0 = *(short8*)&f0i;
      short8 f1 = *(short8*)&f1i;

      // l accumulation on the MFMA pipe: every D-row of ones.P^T = kv-sum
      oacc_l = __builtin_amdgcn_mfma_f32_32x32x16_bf16(ones, f0, oacc_l, 0, 0, 0);
      oacc_l = __builtin_amdgcn_mfma_f32_32x32x16_bf16(ones, f1, oacc_l, 0, 0, 0);

      // --- O^T += V^T P^T ---
#pragma unroll
      for (int dt = 0; dt < 2; ++dt) {
        int d = dt * 32 + l31;
        int p0 = ((kvt * 4 + 0) + lhi) ^ (d & 7);
        int p1 = ((kvt * 4 + 2) + lhi) ^ (d & 7);
        short8 av0 = *(const short8*)(Vts + d * 128 + p0 * 8);
        short8 av1 = *(const short8*)(Vts + d * 128 + p1 * 8);
        oacc[dt] = __builtin_amdgcn_mfma_f32_32x32x16_bf16(av0, f0, oacc[dt], 0, 0, 0);
        oacc[dt] = __builtin_amdgcn_mfma_f32_32x32x16_bf16(av1, f1, oacc[dt], 0, 0, 0);
      }
    }
  }

  float inv = 1.f / oacc_l[0];   // full kv-sum for this lane's q column

  // epilogue: O^T regs -> LDS transpose -> coalesced global store
  __syncthreads();   // everyone done with Ks/Vts
#pragma unroll
  for (int dt = 0; dt < 2; ++dt)
#pragma unroll
    for (int g = 0; g < 4; ++g) {
      int d0 = dt * 32 + g * 8 + lhi * 4;
      float v0 = oacc[dt][4 * g + 0] * inv;
      float v1 = oacc[dt][4 * g + 1] * inv;
      float v2 = oacc[dt][4 * g + 2] * inv;
      float v3 = oacc[dt][4 * g + 3] * inv;
      uint2 pk2;
      pk2.x = (unsigned int)f2bf(v0) | ((unsigned int)f2bf(v1) << 16);
      pk2.y = (unsigned int)f2bf(v2) | ((unsigned int)f2bf(v3) << 16);
      *(uint2*)&Os[(w * 32 + l31) * 72 + d0] = pk2;
    }
  __syncthreads();
#pragma unroll
  for (int pass = 0; pass < 4; ++pass) {
    int e = pass * 256 + tid;
    int row = e >> 3, ch = e & 7;
    int s = qt * 128 + row;
    if (s < S_LEN)
      *(uint4*)&O[base + (size_t)s * NSTATE + ch * 8] = *(const uint4*)&Os[row * 72 + ch * 8];
  }
}

// ---------------------------------------------------------------------------
extern "C" void kernel_launch(void* const* d_in, const int* in_sizes, int n_in,
                              void* d_out, int out_size, void* d_ws, size_t ws_size,
                              hipStream_t stream) {
  const float* x  = (const float*)d_in[0];
  const float* Wq = (const float*)d_in[1];
  const float* bq = (const float*)d_in[2];
  const float* Wk = (const float*)d_in[3];
  const float* Wv = (const float*)d_in[4];
  const float* bv = (const float*)d_in[5];
  const float* Wo = (const float*)d_in[6];
  const float* bo = (const float*)d_in[7];
  float* out = (float*)d_out;

  const size_t NX = (size_t)MROWS * NSTATE;
  const size_t NW = (size_t)NSTATE * NSTATE;

  unsigned short* xb  = (unsigned short*)d_ws;   // dies after proj_qkv
  unsigned short* Wqb = xb  + NX;
  unsigned short* Wkb = Wqb + NW;
  unsigned short* Wvb = Wkb + NW;
  unsigned short* Wob = Wvb + NW;
  unsigned short* q   = Wob + NW;
  unsigned short* k   = q + NX;
  unsigned short* vt  = k + NX;                  // [B,H,D,S_PAD]
  unsigned short* wv  = xb;                      // alias onto dead xb

  dim3 blk(256);
  const size_t n4_total = (NX + 4 * NW) / 4;
  cvt_all<<<dim3((int)(n4_total / 256)), blk, 0, stream>>>(x, Wq, Wk, Wv, Wo, xb);
  proj_qkv<<<dim3(47, 8, 3), blk, 0, stream>>>(xb, Wqb, Wkb, Wvb, bq, bv, q, k, vt);
  attn32t<<<dim3(12, NHEAD, BATCH), blk, 0, stream>>>(q, k, vt, wv);
  proj_o<<<dim3(47, 8, 1), blk, 0, stream>>>(wv, Wob, bo, out);
}

// Round 9
// 267.370 us; speedup vs baseline: 1.0634x; 1.0084x over previous
//
#include <hip/hip_runtime.h>
#include <hip/hip_bf16.h>
#include <stdint.h>

#define S_LEN  1500
#define S_PAD  1536
#define BATCH  4
#define NSTATE 1024
#define NHEAD  16
#define HDIM   64
#define MROWS  6000   // BATCH * S_LEN
#define C1     0.180336879f   // 0.125 * log2(e), folded into q at projection

typedef __attribute__((ext_vector_type(8)))  short short8;    // 8 bf16 = 4 VGPRs
typedef __attribute__((ext_vector_type(4)))  float floatx4;
typedef __attribute__((ext_vector_type(16))) float floatx16;

__device__ __forceinline__ unsigned short f2bf(float f) {
  union { float f; unsigned int u; } v; v.f = f;
  unsigned int r = v.u + 0x7fffu + ((v.u >> 16) & 1u);
  return (unsigned short)(r >> 16);
}

__device__ __forceinline__ unsigned int pkbf2(float a, float b) {
  __hip_bfloat162 h2 = __float22bfloat162_rn(float2{a, b});
  unsigned int u;
  __builtin_memcpy(&u, &h2, 4);
  return u;
}

// async global->LDS, 16B per lane: lane i reads its own global addr, writes
// wave-uniform LDS base + i*16.
__device__ __forceinline__ void gld_lds16(const void* g, void* l) {
  __builtin_amdgcn_global_load_lds(
      (const __attribute__((address_space(1))) void*)g,
      (__attribute__((address_space(3))) void*)l, 16, 0, 0);
}

// ---------------------------------------------------------------------------
// fp32 -> bf16 for x + 4 weight matrices, one launch.
// ---------------------------------------------------------------------------
__global__ __launch_bounds__(256) void cvt_all(
    const float* __restrict__ x,  const float* __restrict__ Wq,
    const float* __restrict__ Wk, const float* __restrict__ Wv,
    const float* __restrict__ Wo, unsigned short* __restrict__ dst)
{
  const size_t NX = (size_t)MROWS * NSTATE;
  size_t e = ((size_t)blockIdx.x * 256 + threadIdx.x) * 4;
  const float* src; size_t off;
  if (e < NX) { src = x; off = e; }
  else {
    size_t t = e - NX;
    int wsel = (int)(t >> 20);           // NW = 2^20
    off = t & ((1u << 20) - 1);
    src = (wsel == 0) ? Wq : (wsel == 1) ? Wk : (wsel == 2) ? Wv : Wo;
  }
  float4 v = *(const float4*)(src + off);
  uint2 o;
  o.x = pkbf2(v.x, v.y);
  o.y = pkbf2(v.z, v.w);
  *(uint2*)(dst + e) = o;
}

// ---------------------------------------------------------------------------
// GEMM: Y[m,n] = (sum_k X[m,k]*W[n,k] + bias[n]) * scale; bf16 in, fp32 accum.
// 128x128 tile, 4 waves, BK=64 as two m97-layout BK=32 half-buffers.
// MODE: 0 = bf16 row-major store, 1 = fp32 row-major store,
//       2 = bf16 store transposed into vt[B,H,D,S_PAD] (V projection).
// Dynamic LDS (34816 B) so multiple template instantiations share ONE block.
// ---------------------------------------------------------------------------
template <int MODE>
__device__ __forceinline__ void gemm128_bt(
    const unsigned short* __restrict__ X,
    const unsigned short* __restrict__ W,
    const float* __restrict__ bias,
    void* __restrict__ Yv,
    int m0, int n0, float scale)
{
  extern __shared__ unsigned short SM[];   // >= 17408 shorts (34816 B)
  unsigned short* Asp = SM;            // As[h] = Asp + h*4096
  unsigned short* Bsp = SM + 8192;     // Bs[h] = Bsp + h*4096

  const int tid  = threadIdx.x;
  const int lane = tid & 63;
  const int wid  = tid >> 6;
  const int wm   = (wid & 1) * 64;
  const int wn   = (wid >> 1) * 64;
  const int l15  = lane & 15;
  const int l4   = lane >> 4;

  floatx4 acc[4][4];
#pragma unroll
  for (int i = 0; i < 4; ++i)
#pragma unroll
    for (int j = 0; j < 4; ++j)
      acc[i][j] = (floatx4){0.f, 0.f, 0.f, 0.f};

  const int srow  = tid >> 2;        // 0..63
  const int scolb = (tid & 3) * 16;  // byte offset within 64B K-row

  const char* xrp[2];
  const char* wrp[2];
#pragma unroll
  for (int r = 0; r < 2; ++r) {
    int arow = m0 + r * 64 + srow;
    if (arow > MROWS - 1) arow = MROWS - 1;
    xrp[r] = (const char*)X + (size_t)arow * NSTATE * 2 + scolb;
    int brow = n0 + r * 64 + srow;   // N always full
    wrp[r] = (const char*)W + (size_t)brow * NSTATE * 2 + scolb;
  }

  for (int k0 = 0; k0 < NSTATE; k0 += 64) {
    __syncthreads();
#pragma unroll
    for (int h = 0; h < 2; ++h) {
      int kb = (k0 + h * 32) * 2;
#pragma unroll
      for (int r = 0; r < 2; ++r) {
        gld_lds16(xrp[r] + kb, (char*)SM + h * 8192 + r * 4096 + wid * 1024);
        gld_lds16(wrp[r] + kb, (char*)SM + 16384 + h * 8192 + r * 4096 + wid * 1024);
      }
    }
    __syncthreads();

#pragma unroll
    for (int h = 0; h < 2; ++h) {
      const unsigned short* Ah = Asp + h * 4096;
      const unsigned short* Bh = Bsp + h * 4096;
      short8 a[4], b[4];
#pragma unroll
      for (int i = 0; i < 4; ++i)
        a[i] = *(const short8*)(Ah + (wm + i * 16 + l15) * 32 + l4 * 8);
#pragma unroll
      for (int j = 0; j < 4; ++j)
        b[j] = *(const short8*)(Bh + (wn + j * 16 + l15) * 32 + l4 * 8);
#pragma unroll
      for (int i = 0; i < 4; ++i)
#pragma unroll
        for (int j = 0; j < 4; ++j)
          acc[i][j] = __builtin_amdgcn_mfma_f32_16x16x32_bf16(a[i], b[j], acc[i][j], 0, 0, 0);
    }
  }

  if (MODE != 2) {
    // epilogue: C/D layout row=(lane>>4)*4+r, col=lane&15
#pragma unroll
    for (int j = 0; j < 4; ++j) {
      int ng = n0 + wn + j * 16 + l15;
      float bias_v = bias ? bias[ng] : 0.f;
#pragma unroll
      for (int i = 0; i < 4; ++i) {
        int mgb = m0 + wm + i * 16 + l4 * 4;
#pragma unroll
        for (int r = 0; r < 4; ++r) {
          int mg = mgb + r;
          if (mg < MROWS) {
            float val = (acc[i][j][r] + bias_v) * scale;
            if (MODE == 1) ((float*)Yv)[(size_t)mg * NSTATE + ng] = val;
            else           ((unsigned short*)Yv)[(size_t)mg * NSTATE + ng] = f2bf(val);
          }
        }
      }
    }
  } else {
    // V projection: transpose through LDS, store vt[((b*16+h)*64+d)*S_PAD + s]
    unsigned short* vt = (unsigned short*)Yv;
    __syncthreads();   // staging LDS dead now
#pragma unroll
    for (int j = 0; j < 4; ++j) {
      int nl = wn + j * 16 + l15;
      float bias_v = bias[n0 + nl];
#pragma unroll
      for (int i = 0; i < 4; ++i) {
        int mlb = wm + i * 16 + l4 * 4;
#pragma unroll
        for (int r = 0; r < 4; ++r)
          SM[nl * 136 + mlb + r] = f2bf(acc[i][j][r] + bias_v);
      }
    }
    __syncthreads();
#pragma unroll
    for (int pass = 0; pass < 8; ++pass) {
      int e   = pass * 256 + tid;      // 0..2047
      int nl  = e >> 4;                // 0..127
      int m0l = (e & 15) * 8;          // 0..120
      int ng  = n0 + nl;
      int hh  = ng >> 6, dd = ng & 63;
      int mg  = m0 + m0l;
      int b1  = mg / 1500;
      int s1  = mg - b1 * 1500;
      if (mg + 7 < MROWS && s1 + 7 < S_LEN) {
        *(uint4*)&vt[(((size_t)b1 * NHEAD + hh) * HDIM + dd) * S_PAD + s1] =
            *(const uint4*)&SM[nl * 136 + m0l];
      } else {
#pragma unroll
        for (int jj = 0; jj < 8; ++jj) {
          int m = mg + jj;
          if (m < MROWS) {
            int b2 = m / 1500;
            int s2 = m - b2 * 1500;
            vt[(((size_t)b2 * NHEAD + hh) * HDIM + dd) * S_PAD + s2] =
                SM[nl * 136 + m0l + jj];
          }
        }
      }
    }
  }
}

// grid: (m-tiles=47, n-tiles=8, z=3) -- m-major dispatch (round-5 measured best)
__global__ __launch_bounds__(256) void proj_qkv(
    const unsigned short* __restrict__ X,
    const unsigned short* __restrict__ Wq, const unsigned short* __restrict__ Wk,
    const unsigned short* __restrict__ Wv,
    const float* __restrict__ bq, const float* __restrict__ bv,
    unsigned short* __restrict__ q, unsigned short* __restrict__ k,
    unsigned short* __restrict__ vt)
{
  const int z = blockIdx.z;
  const int m0 = blockIdx.x * 128, n0 = blockIdx.y * 128;
  if (z == 0)      gemm128_bt<0>(X, Wq, bq,      q,  m0, n0, C1);
  else if (z == 1) gemm128_bt<0>(X, Wk, nullptr, k,  m0, n0, 1.0f);
  else             gemm128_bt<2>(X, Wv, bv,      vt, m0, n0, 1.0f);
}

__global__ __launch_bounds__(256) void proj_o(
    const unsigned short* __restrict__ X, const unsigned short* __restrict__ W,
    const float* __restrict__ bias, float* __restrict__ Y)
{
  gemm128_bt<1>(X, W, bias, Y, blockIdx.x * 128, blockIdx.y * 128, 1.0f);
}

// ---------------------------------------------------------------------------
// Flash attention, transposed-score form (32x32x16 MFMA), shuffle-free P.
//   S^T = K . Q^T with K rows permuted by sigma (swap bits 2,3 of l31):
//   the C-layout output then IS the PV B-fragment layout per lane -- P
//   fragments are straight cvt_pk(exp2) of sacc regs, no cross-lane moves.
//   O^T = V^T . P^T; l via ones-row MFMA (exact compensation of RNE-rounded P)
// ---------------------------------------------------------------------------
__global__ __launch_bounds__(256, 4) void attn32t(
    const unsigned short* __restrict__ Q, const unsigned short* __restrict__ K,
    const unsigned short* __restrict__ VT, unsigned short* __restrict__ O)
{
  __shared__ unsigned short SMEM[16384];      // 32 KB
  unsigned short* Ks  = SMEM;                 // [128 kv][64 d], 16B-chunk xor-swizzled
  unsigned short* Vts = SMEM + 8192;          // [64 d][128 kv], 16B-chunk xor-swizzled
  unsigned short* Os  = SMEM;                 // epilogue overlay [128 q][72]

  const int tid  = threadIdx.x;
  const int lane = tid & 63;
  const int w    = tid >> 6;
  const int l31  = lane & 31;
  const int lhi  = lane >> 5;
  const int qt = blockIdx.x, h = blockIdx.y, b = blockIdx.z;
  const size_t base  = ((size_t)b * S_LEN) * NSTATE + h * HDIM;
  const size_t vbase = (((size_t)b * NHEAD + h) * HDIM) * S_PAD;

  // sigma: swap bits 2 and 3 of l31 (row-group 1<->2, 5<->6)
  const int sg = (l31 & 19) | ((l31 & 4) << 1) | ((l31 & 8) >> 1);

  // Q fragments (B-operand): lane holds Q[q=l31][d = c*16 + lhi*8 + j]
  short8 qf[4];
  {
    int qrow = qt * 128 + w * 32 + l31;
    if (qrow > S_LEN - 1) qrow = S_LEN - 1;
    const unsigned short* qp = Q + base + (size_t)qrow * NSTATE;
#pragma unroll
    for (int c = 0; c < 4; ++c)
      qf[c] = *(const short8*)(qp + c * 16 + lhi * 8);
  }

  // all-ones A fragment (bf16 1.0) for the l-accumulating MFMA
  short8 ones;
#pragma unroll
  for (int i = 0; i < 8; ++i) ones[i] = (short)0x3F80;

  floatx16 oacc[2], oacc_l;
  oacc[0] = (floatx16)(0.f);
  oacc[1] = (floatx16)(0.f);
  oacc_l  = (floatx16)(0.f);

  for (int t = 0; t < 12; ++t) {
    __syncthreads();   // previous tile fully consumed
    // stage K tile 128x64: call = 8 rows x 8 chunks, phys chunk = logical^(row&7)
#pragma unroll
    for (int qq = 0; qq < 4; ++qq) {
      int row  = (w * 4 + qq) * 8 + (lane >> 3);
      int logc = (lane & 7) ^ (row & 7);
      int s = t * 128 + row; if (s > S_LEN - 1) s = S_LEN - 1;
      gld_lds16(&K[base + (size_t)s * NSTATE + logc * 8],
                (char*)Ks + (w * 4 + qq) * 1024);
    }
    // stage Vt tile 64x128: call = 4 rows x 16 chunks, phys = logical^(d&7)
#pragma unroll
    for (int qq = 0; qq < 4; ++qq) {
      int d    = (w * 4 + qq) * 4 + (lane >> 4);
      int logc = (lane & 15) ^ (d & 7);
      gld_lds16(&VT[vbase + (size_t)d * S_PAD + t * 128 + logc * 8],
                (char*)Vts + (w * 4 + qq) * 1024);
    }
    __syncthreads();

#pragma unroll
    for (int kvt = 0; kvt < 4; ++kvt) {
      // --- S^T tile: 32 kv (sigma-permuted rows) x 32 q ---
      floatx16 sacc = (floatx16)(0.f);
      int prow = kvt * 32 + sg;
#pragma unroll
      for (int c = 0; c < 4; ++c) {
        int phys = (c * 2 + lhi) ^ (sg & 7);
        short8 ak = *(const short8*)(Ks + prow * 64 + phys * 8);
        sacc = __builtin_amdgcn_mfma_f32_32x32x16_bf16(ak, qf[c], sacc, 0, 0, 0);
      }

      // kv masking (tail groups 3/7 are sigma-invariant: same regs as before)
      if (t == 11 && kvt >= 2) {
        if (kvt == 3) {
#pragma unroll
          for (int r = 0; r < 16; ++r) sacc[r] = -3.0e38f;
        } else {
#pragma unroll
          for (int r = 12; r < 16; ++r) sacc[r] = lhi ? -3.0e38f : sacc[r];
        }
      }

      // P^T B-fragments directly: f0 regs = kv lhi*8+0..7, f1 = +16
      unsigned int f0i[4], f1i[4];
#pragma unroll
      for (int i = 0; i < 4; ++i) {
        f0i[i] = pkbf2(exp2f(sacc[2 * i]),     exp2f(sacc[2 * i + 1]));
        f1i[i] = pkbf2(exp2f(sacc[8 + 2 * i]), exp2f(sacc[9 + 2 * i]));
      }
      short8 f0, f1;
      __builtin_memcpy(&f0, f0i, 16);
      __builtin_memcpy(&f1, f1i, 16);

      // l accumulation on the MFMA pipe: every D-row of ones.P^T = kv-sum
      oacc_l = __builtin_amdgcn_mfma_f32_32x32x16_bf16(ones, f0, oacc_l, 0, 0, 0);
      oacc_l = __builtin_amdgcn_mfma_f32_32x32x16_bf16(ones, f1, oacc_l, 0, 0, 0);

      // --- O^T += V^T P^T ---
#pragma unroll
      for (int dt = 0; dt < 2; ++dt) {
        int d = dt * 32 + l31;
        int p0 = ((kvt * 4 + 0) + lhi) ^ (d & 7);
        int p1 = ((kvt * 4 + 2) + lhi) ^ (d & 7);
        short8 av0 = *(const short8*)(Vts + d * 128 + p0 * 8);
        short8 av1 = *(const short8*)(Vts + d * 128 + p1 * 8);
        oacc[dt] = __builtin_amdgcn_mfma_f32_32x32x16_bf16(av0, f0, oacc[dt], 0, 0, 0);
        oacc[dt] = __builtin_amdgcn_mfma_f32_32x32x16_bf16(av1, f1, oacc[dt], 0, 0, 0);
      }
    }
  }

  float inv = 1.f / oacc_l[0];   // full kv-sum for this lane's q column

  // epilogue: O^T regs -> LDS transpose -> coalesced global store
  __syncthreads();   // everyone done with Ks/Vts
#pragma unroll
  for (int dt = 0; dt < 2; ++dt)
#pragma unroll
    for (int g = 0; g < 4; ++g) {
      int d0 = dt * 32 + g * 8 + lhi * 4;
      float v0 = oacc[dt][4 * g + 0] * inv;
      float v1 = oacc[dt][4 * g + 1] * inv;
      float v2 = oacc[dt][4 * g + 2] * inv;
      float v3 = oacc[dt][4 * g + 3] * inv;
      uint2 pk2;
      pk2.x = (unsigned int)f2bf(v0) | ((unsigned int)f2bf(v1) << 16);
      pk2.y = (unsigned int)f2bf(v2) | ((unsigned int)f2bf(v3) << 16);
      *(uint2*)&Os[(w * 32 + l31) * 72 + d0] = pk2;
    }
  __syncthreads();
#pragma unroll
  for (int pass = 0; pass < 4; ++pass) {
    int e = pass * 256 + tid;
    int row = e >> 3, ch = e & 7;
    int s = qt * 128 + row;
    if (s < S_LEN)
      *(uint4*)&O[base + (size_t)s * NSTATE + ch * 8] = *(const uint4*)&Os[row * 72 + ch * 8];
  }
}

// ---------------------------------------------------------------------------
extern "C" void kernel_launch(void* const* d_in, const int* in_sizes, int n_in,
                              void* d_out, int out_size, void* d_ws, size_t ws_size,
                              hipStream_t stream) {
  const float* x  = (const float*)d_in[0];
  const float* Wq = (const float*)d_in[1];
  const float* bq = (const float*)d_in[2];
  const float* Wk = (const float*)d_in[3];
  const float* Wv = (const float*)d_in[4];
  const float* bv = (const float*)d_in[5];
  const float* Wo = (const float*)d_in[6];
  const float* bo = (const float*)d_in[7];
  float* out = (float*)d_out;

  const size_t NX = (size_t)MROWS * NSTATE;
  const size_t NW = (size_t)NSTATE * NSTATE;

  unsigned short* xb  = (unsigned short*)d_ws;   // dies after proj_qkv
  unsigned short* Wqb = xb  + NX;
  unsigned short* Wkb = Wqb + NW;
  unsigned short* Wvb = Wkb + NW;
  unsigned short* Wob = Wvb + NW;
  unsigned short* q   = Wob + NW;
  unsigned short* k   = q + NX;
  unsigned short* vt  = k + NX;                  // [B,H,D,S_PAD]
  unsigned short* wv  = xb;                      // alias onto dead xb

  dim3 blk(256);
  const size_t n4_total = (NX + 4 * NW) / 4;
  cvt_all<<<dim3((int)(n4_total / 256)), blk, 0, stream>>>(x, Wq, Wk, Wv, Wo, xb);
  proj_qkv<<<dim3(47, 8, 3), blk, 34816, stream>>>(xb, Wqb, Wkb, Wvb, bq, bv, q, k, vt);
  attn32t<<<dim3(12, NHEAD, BATCH), blk, 0, stream>>>(q, k, vt, wv);
  proj_o<<<dim3(47, 8, 1), blk, 34816, stream>>>(wv, Wob, bo, out);
}